// Round 1
// baseline (1430.959 us; speedup 1.0000x reference)
//
#include <hip/hip_runtime.h>

#define N_NODES 100000
#define N_EDGES 1600000
#define D_FEAT 64

// 16 threads per edge; each thread handles 4 consecutive floats (float4).
// Gather of H[col] is coalesced: 16 lanes x 16B = 256B contiguous per edge.
__global__ __launch_bounds__(256) void spmm_coo_atomic(
    const float* __restrict__ H,
    const float* __restrict__ vals,
    const int* __restrict__ rows,
    const int* __restrict__ cols,
    float* __restrict__ out)
{
    long long t = (long long)blockIdx.x * blockDim.x + threadIdx.x;
    const long long total = (long long)N_EDGES * 16;
    if (t >= total) return;

    int e  = (int)(t >> 4);   // edge index
    int fc = (int)(t & 15);   // feature chunk (4 floats each)

    float v = vals[e];
    int r = rows[e];
    int c = cols[e];

    const float4 h = *reinterpret_cast<const float4*>(H + (long long)c * D_FEAT + fc * 4);
    float* o = out + (long long)r * D_FEAT + fc * 4;

    atomicAdd(o + 0, v * h.x);
    atomicAdd(o + 1, v * h.y);
    atomicAdd(o + 2, v * h.z);
    atomicAdd(o + 3, v * h.w);
}

extern "C" void kernel_launch(void* const* d_in, const int* in_sizes, int n_in,
                              void* d_out, int out_size, void* d_ws, size_t ws_size,
                              hipStream_t stream) {
    const float* H    = (const float*)d_in[0];  // [N_NODES, D_FEAT]
    const float* vals = (const float*)d_in[1];  // [N_EDGES]
    const int*   rows = (const int*)d_in[2];    // [N_EDGES]
    const int*   cols = (const int*)d_in[3];    // [N_EDGES]
    float* out = (float*)d_out;                 // [N_NODES, D_FEAT]

    // d_out is poisoned to 0xAA before every launch — zero it ourselves.
    hipMemsetAsync(out, 0, (size_t)out_size * sizeof(float), stream);

    const long long total = (long long)N_EDGES * 16;
    const int block = 256;
    const long long grid = (total + block - 1) / block;
    spmm_coo_atomic<<<(dim3)(unsigned)grid, block, 0, stream>>>(H, vals, rows, cols, out);
}

// Round 2
// 353.566 us; speedup vs baseline: 4.0472x; 4.0472x over previous
//
#include <hip/hip_runtime.h>

#define N_NODES 100000
#define N_EDGES 1600000
#define D_FEAT 64

#define SCAN_BLOCK 1024
#define SCAN_GRID  ((N_NODES + SCAN_BLOCK - 1) / SCAN_BLOCK)   // 98

// ---------------- histogram: counts[r]++ over edges ----------------
__global__ __launch_bounds__(256) void hist_kernel(
    const int* __restrict__ rows, int* __restrict__ counts)
{
    int i = blockIdx.x * blockDim.x + threadIdx.x;
    int stride = gridDim.x * blockDim.x;
    for (int e = i; e < N_EDGES; e += stride)
        atomicAdd(&counts[rows[e]], 1);
}

// ---------------- scan phase A: per-block exclusive scan ----------------
// counts[N] -> row_ptr[i] = local exclusive scan; blocksums[b] = block total
__global__ __launch_bounds__(SCAN_BLOCK) void scanA_kernel(
    const int* __restrict__ counts, int* __restrict__ row_ptr,
    int* __restrict__ blocksums)
{
    __shared__ int buf[2][SCAN_BLOCK];
    int tid = threadIdx.x;
    int gid = blockIdx.x * SCAN_BLOCK + tid;
    int v = (gid < N_NODES) ? counts[gid] : 0;
    buf[0][tid] = v;
    __syncthreads();
    int src = 0;
    for (int off = 1; off < SCAN_BLOCK; off <<= 1) {
        int dst = 1 - src;
        int x = buf[src][tid];
        if (tid >= off) x += buf[src][tid - off];
        buf[dst][tid] = x;
        __syncthreads();
        src = dst;
    }
    // inclusive -> exclusive
    int incl = buf[src][tid];
    int excl = incl - v;
    if (gid < N_NODES) row_ptr[gid] = excl;
    if (tid == SCAN_BLOCK - 1) blocksums[blockIdx.x] = incl;
}

// ---------------- scan phase B: scan the 98 block sums (1 block) -----------
__global__ __launch_bounds__(128) void scanB_kernel(int* __restrict__ blocksums)
{
    __shared__ int buf[2][128];
    int tid = threadIdx.x;
    int v = (tid < SCAN_GRID) ? blocksums[tid] : 0;
    buf[0][tid] = v;
    __syncthreads();
    int src = 0;
    for (int off = 1; off < 128; off <<= 1) {
        int dst = 1 - src;
        int x = buf[src][tid];
        if (tid >= off) x += buf[src][tid - off];
        buf[dst][tid] = x;
        __syncthreads();
        src = dst;
    }
    int excl = buf[src][tid] - v;
    if (tid < SCAN_GRID) blocksums[tid] = excl;
}

// ---------------- scan phase C: add offsets; init cursor; row_ptr[N]=E ------
__global__ __launch_bounds__(SCAN_BLOCK) void scanC_kernel(
    int* __restrict__ row_ptr, const int* __restrict__ blocksums,
    int* __restrict__ cursor)
{
    int gid = blockIdx.x * SCAN_BLOCK + threadIdx.x;
    if (gid < N_NODES) {
        int p = row_ptr[gid] + blocksums[blockIdx.x];
        row_ptr[gid] = p;
        cursor[gid] = p;
    }
    if (gid == 0) row_ptr[N_NODES] = N_EDGES;
}

// ---------------- counting-sort scatter into CSR order ----------------
__global__ __launch_bounds__(256) void scatter_kernel(
    const float* __restrict__ vals, const int* __restrict__ rows,
    const int* __restrict__ cols, int* __restrict__ cursor,
    float* __restrict__ vals_s, int* __restrict__ cols_s)
{
    int i = blockIdx.x * blockDim.x + threadIdx.x;
    int stride = gridDim.x * blockDim.x;
    for (int e = i; e < N_EDGES; e += stride) {
        int r = rows[e];
        int pos = atomicAdd(&cursor[r], 1);
        vals_s[pos] = vals[e];
        cols_s[pos] = cols[e];
    }
}

// ---------------- gather SpMM: 16 lanes per row, float4 each ----------------
__global__ __launch_bounds__(256) void gather_kernel(
    const float* __restrict__ H, const float* __restrict__ vals_s,
    const int* __restrict__ cols_s, const int* __restrict__ row_ptr,
    float* __restrict__ out)
{
    int row = blockIdx.x * 16 + (threadIdx.x >> 4);
    int fc  = threadIdx.x & 15;
    if (row >= N_NODES) return;

    int start = row_ptr[row];
    int end   = row_ptr[row + 1];

    const float4* H4 = reinterpret_cast<const float4*>(H);
    float4 acc = make_float4(0.f, 0.f, 0.f, 0.f);
    for (int e = start; e < end; ++e) {
        float v = vals_s[e];
        int   c = cols_s[e];
        float4 h = H4[(long long)c * 16 + fc];
        acc.x += v * h.x;
        acc.y += v * h.y;
        acc.z += v * h.z;
        acc.w += v * h.w;
    }
    reinterpret_cast<float4*>(out)[(long long)row * 16 + fc] = acc;
}

extern "C" void kernel_launch(void* const* d_in, const int* in_sizes, int n_in,
                              void* d_out, int out_size, void* d_ws, size_t ws_size,
                              hipStream_t stream) {
    const float* H    = (const float*)d_in[0];
    const float* vals = (const float*)d_in[1];
    const int*   rows = (const int*)d_in[2];
    const int*   cols = (const int*)d_in[3];
    float* out = (float*)d_out;

    // workspace layout (4-byte elements)
    char* ws = (char*)d_ws;
    int*   row_ptr   = (int*)ws;                               // N+1
    int*   cursor    = row_ptr + (N_NODES + 1);                // N (also counts)
    int*   blocksums = cursor + N_NODES;                       // SCAN_GRID
    int*   cols_s    = blocksums + ((SCAN_GRID + 31) & ~31);   // E
    float* vals_s    = (float*)(cols_s + N_EDGES);             // E

    int* counts = cursor;  // reuse cursor region for histogram counts

    hipMemsetAsync(counts, 0, N_NODES * sizeof(int), stream);

    hist_kernel<<<512, 256, 0, stream>>>(rows, counts);
    scanA_kernel<<<SCAN_GRID, SCAN_BLOCK, 0, stream>>>(counts, row_ptr, blocksums);
    scanB_kernel<<<1, 128, 0, stream>>>(blocksums);
    scanC_kernel<<<SCAN_GRID, SCAN_BLOCK, 0, stream>>>(row_ptr, blocksums, cursor);
    scatter_kernel<<<512, 256, 0, stream>>>(vals, rows, cols, cursor, vals_s, cols_s);

    int gather_grid = (N_NODES + 15) / 16;  // 16 rows per 256-thread block
    gather_kernel<<<gather_grid, 256, 0, stream>>>(H, vals_s, cols_s, row_ptr, out);
}

// Round 3
// 338.569 us; speedup vs baseline: 4.2265x; 1.0443x over previous
//
#include <hip/hip_runtime.h>

#define N_NODES 100000
#define N_EDGES 1600000
#define D_FEAT 64

#define SCAN_BLOCK 1024
#define SCAN_GRID  ((N_NODES + SCAN_BLOCK - 1) / SCAN_BLOCK)   // 98

// ---------------- histogram: counts[r]++ over edges ----------------
__global__ __launch_bounds__(256) void hist_kernel(
    const int* __restrict__ rows, int* __restrict__ counts)
{
    int i = blockIdx.x * blockDim.x + threadIdx.x;
    int stride = gridDim.x * blockDim.x;
    for (int e = i; e < N_EDGES; e += stride)
        atomicAdd(&counts[rows[e]], 1);
}

// ---------------- scan phase A: per-block exclusive scan ----------------
__global__ __launch_bounds__(SCAN_BLOCK) void scanA_kernel(
    const int* __restrict__ counts, int* __restrict__ row_ptr,
    int* __restrict__ blocksums)
{
    __shared__ int buf[2][SCAN_BLOCK];
    int tid = threadIdx.x;
    int gid = blockIdx.x * SCAN_BLOCK + tid;
    int v = (gid < N_NODES) ? counts[gid] : 0;
    buf[0][tid] = v;
    __syncthreads();
    int src = 0;
    for (int off = 1; off < SCAN_BLOCK; off <<= 1) {
        int dst = 1 - src;
        int x = buf[src][tid];
        if (tid >= off) x += buf[src][tid - off];
        buf[dst][tid] = x;
        __syncthreads();
        src = dst;
    }
    int incl = buf[src][tid];
    int excl = incl - v;
    if (gid < N_NODES) row_ptr[gid] = excl;
    if (tid == SCAN_BLOCK - 1) blocksums[blockIdx.x] = incl;
}

// ---------------- scan phase B: scan the 98 block sums (1 block) -----------
__global__ __launch_bounds__(128) void scanB_kernel(int* __restrict__ blocksums)
{
    __shared__ int buf[2][128];
    int tid = threadIdx.x;
    int v = (tid < SCAN_GRID) ? blocksums[tid] : 0;
    buf[0][tid] = v;
    __syncthreads();
    int src = 0;
    for (int off = 1; off < 128; off <<= 1) {
        int dst = 1 - src;
        int x = buf[src][tid];
        if (tid >= off) x += buf[src][tid - off];
        buf[dst][tid] = x;
        __syncthreads();
        src = dst;
    }
    int excl = buf[src][tid] - v;
    if (tid < SCAN_GRID) blocksums[tid] = excl;
}

// ---------------- scan phase C: add offsets; init cursor; row_ptr[N]=E ------
__global__ __launch_bounds__(SCAN_BLOCK) void scanC_kernel(
    int* __restrict__ row_ptr, const int* __restrict__ blocksums,
    int* __restrict__ cursor)
{
    int gid = blockIdx.x * SCAN_BLOCK + threadIdx.x;
    if (gid < N_NODES) {
        int p = row_ptr[gid] + blocksums[blockIdx.x];
        row_ptr[gid] = p;
        cursor[gid] = p;
    }
    if (gid == 0) row_ptr[N_NODES] = N_EDGES;
}

// ---------------- counting-sort scatter: one 8B record per edge ----------------
__global__ __launch_bounds__(256) void scatter_kernel(
    const float* __restrict__ vals, const int* __restrict__ rows,
    const int* __restrict__ cols, int* __restrict__ cursor,
    int2* __restrict__ rec)
{
    int i = blockIdx.x * blockDim.x + threadIdx.x;
    int stride = gridDim.x * blockDim.x;
    for (int e = i; e < N_EDGES; e += stride) {
        int r = rows[e];
        int pos = atomicAdd(&cursor[r], 1);
        rec[pos] = make_int2(cols[e], __float_as_int(vals[e]));
    }
}

// ---------------- gather SpMM: 16 lanes per row, float4 each, unroll 4 -------
__global__ __launch_bounds__(256) void gather_kernel(
    const float* __restrict__ H, const int2* __restrict__ rec,
    const int* __restrict__ row_ptr, float* __restrict__ out)
{
    int row = blockIdx.x * 16 + (threadIdx.x >> 4);
    int fc  = threadIdx.x & 15;
    if (row >= N_NODES) return;

    int start = row_ptr[row];
    int n     = row_ptr[row + 1] - start;
    const int2* R = rec + start;
    const float4* H4 = reinterpret_cast<const float4*>(H);

    float4 acc = make_float4(0.f, 0.f, 0.f, 0.f);
    int e = 0;
    for (; e + 4 <= n; e += 4) {
        int2 r0 = R[e + 0];
        int2 r1 = R[e + 1];
        int2 r2 = R[e + 2];
        int2 r3 = R[e + 3];
        float4 h0 = H4[(long long)r0.x * 16 + fc];
        float4 h1 = H4[(long long)r1.x * 16 + fc];
        float4 h2 = H4[(long long)r2.x * 16 + fc];
        float4 h3 = H4[(long long)r3.x * 16 + fc];
        float v0 = __int_as_float(r0.y);
        float v1 = __int_as_float(r1.y);
        float v2 = __int_as_float(r2.y);
        float v3 = __int_as_float(r3.y);
        acc.x += v0 * h0.x; acc.y += v0 * h0.y; acc.z += v0 * h0.z; acc.w += v0 * h0.w;
        acc.x += v1 * h1.x; acc.y += v1 * h1.y; acc.z += v1 * h1.z; acc.w += v1 * h1.w;
        acc.x += v2 * h2.x; acc.y += v2 * h2.y; acc.z += v2 * h2.z; acc.w += v2 * h2.w;
        acc.x += v3 * h3.x; acc.y += v3 * h3.y; acc.z += v3 * h3.z; acc.w += v3 * h3.w;
    }
    for (; e < n; ++e) {
        int2 r0 = R[e];
        float4 h0 = H4[(long long)r0.x * 16 + fc];
        float v0 = __int_as_float(r0.y);
        acc.x += v0 * h0.x; acc.y += v0 * h0.y; acc.z += v0 * h0.z; acc.w += v0 * h0.w;
    }
    reinterpret_cast<float4*>(out)[(long long)row * 16 + fc] = acc;
}

extern "C" void kernel_launch(void* const* d_in, const int* in_sizes, int n_in,
                              void* d_out, int out_size, void* d_ws, size_t ws_size,
                              hipStream_t stream) {
    const float* H    = (const float*)d_in[0];
    const float* vals = (const float*)d_in[1];
    const int*   rows = (const int*)d_in[2];
    const int*   cols = (const int*)d_in[3];
    float* out = (float*)d_out;

    // workspace layout: rec first (8B aligned), then int arrays
    char* ws = (char*)d_ws;
    int2* rec       = (int2*)ws;                          // E * 8B
    int*  row_ptr   = (int*)(rec + N_EDGES);              // N+1
    int*  cursor    = row_ptr + (N_NODES + 1);            // N
    int*  blocksums = cursor + N_NODES;                   // SCAN_GRID

    int* counts = cursor;  // histogram counts live in cursor region

    hipMemsetAsync(counts, 0, N_NODES * sizeof(int), stream);

    hist_kernel<<<512, 256, 0, stream>>>(rows, counts);
    scanA_kernel<<<SCAN_GRID, SCAN_BLOCK, 0, stream>>>(counts, row_ptr, blocksums);
    scanB_kernel<<<1, 128, 0, stream>>>(blocksums);
    scanC_kernel<<<SCAN_GRID, SCAN_BLOCK, 0, stream>>>(row_ptr, blocksums, cursor);
    scatter_kernel<<<512, 256, 0, stream>>>(vals, rows, cols, cursor, rec);

    int gather_grid = (N_NODES + 15) / 16;  // 16 rows per 256-thread block
    gather_kernel<<<gather_grid, 256, 0, stream>>>(H, rec, row_ptr, out);
}

// Round 4
// 307.814 us; speedup vs baseline: 4.6488x; 1.0999x over previous
//
#include <hip/hip_runtime.h>

#define N_NODES 100000
#define N_EDGES 1600000
#define D_FEAT 64

#define N_PART 8                                   // one partition per XCD
#define ROWS_PER_PART ((N_NODES + N_PART - 1) / N_PART)  // 12500

#define SCAN_BLOCK 1024
#define SCAN_GRID  ((N_NODES + SCAN_BLOCK - 1) / SCAN_BLOCK)   // 98

// ---------------- histogram, XCD-partitioned by row range ----------------
// blocks with (blockIdx & 7)==p only count rows in partition p, so counter
// lines are only touched by one XCD's L2 (no cross-XCD line bouncing).
__global__ __launch_bounds__(256) void hist_kernel(
    const int* __restrict__ rows, int* __restrict__ counts)
{
    int part = blockIdx.x & (N_PART - 1);
    int blk  = blockIdx.x >> 3;
    int nblk = gridDim.x >> 3;
    int lo = part * ROWS_PER_PART;
    int hi = lo + ROWS_PER_PART;   // N divides evenly (100000 = 8*12500)

    int i = blk * blockDim.x + threadIdx.x;
    int stride = nblk * blockDim.x;
    for (int e = i; e < N_EDGES; e += stride) {
        int r = rows[e];
        if (r >= lo && r < hi)
            atomicAdd(&counts[r], 1);
    }
}

// ---------------- scan phase A: per-block exclusive scan ----------------
__global__ __launch_bounds__(SCAN_BLOCK) void scanA_kernel(
    const int* __restrict__ counts, int* __restrict__ row_ptr,
    int* __restrict__ blocksums)
{
    __shared__ int buf[2][SCAN_BLOCK];
    int tid = threadIdx.x;
    int gid = blockIdx.x * SCAN_BLOCK + tid;
    int v = (gid < N_NODES) ? counts[gid] : 0;
    buf[0][tid] = v;
    __syncthreads();
    int src = 0;
    for (int off = 1; off < SCAN_BLOCK; off <<= 1) {
        int dst = 1 - src;
        int x = buf[src][tid];
        if (tid >= off) x += buf[src][tid - off];
        buf[dst][tid] = x;
        __syncthreads();
        src = dst;
    }
    int incl = buf[src][tid];
    int excl = incl - v;
    if (gid < N_NODES) row_ptr[gid] = excl;
    if (tid == SCAN_BLOCK - 1) blocksums[blockIdx.x] = incl;
}

// ---------------- scan phase B: scan the 98 block sums (1 block) -----------
__global__ __launch_bounds__(128) void scanB_kernel(int* __restrict__ blocksums)
{
    __shared__ int buf[2][128];
    int tid = threadIdx.x;
    int v = (tid < SCAN_GRID) ? blocksums[tid] : 0;
    buf[0][tid] = v;
    __syncthreads();
    int src = 0;
    for (int off = 1; off < 128; off <<= 1) {
        int dst = 1 - src;
        int x = buf[src][tid];
        if (tid >= off) x += buf[src][tid - off];
        buf[dst][tid] = x;
        __syncthreads();
        src = dst;
    }
    int excl = buf[src][tid] - v;
    if (tid < SCAN_GRID) blocksums[tid] = excl;
}

// ---------------- scan phase C: add offsets; init cursor; row_ptr[N]=E ------
__global__ __launch_bounds__(SCAN_BLOCK) void scanC_kernel(
    int* __restrict__ row_ptr, const int* __restrict__ blocksums,
    int* __restrict__ cursor)
{
    int gid = blockIdx.x * SCAN_BLOCK + threadIdx.x;
    if (gid < N_NODES) {
        int p = row_ptr[gid] + blocksums[blockIdx.x];
        row_ptr[gid] = p;
        cursor[gid] = p;
    }
    if (gid == 0) row_ptr[N_NODES] = N_EDGES;
}

// ---------------- counting-sort scatter, XCD-partitioned by row range -------
// All writes to a given rec line come from one partition (= one XCD under
// round-robin dispatch) -> the line stays in that XCD's L2 until complete.
__global__ __launch_bounds__(256) void scatter_kernel(
    const float* __restrict__ vals, const int* __restrict__ rows,
    const int* __restrict__ cols, int* __restrict__ cursor,
    int2* __restrict__ rec)
{
    int part = blockIdx.x & (N_PART - 1);
    int blk  = blockIdx.x >> 3;
    int nblk = gridDim.x >> 3;
    int lo = part * ROWS_PER_PART;
    int hi = lo + ROWS_PER_PART;

    int i = blk * blockDim.x + threadIdx.x;
    int stride = nblk * blockDim.x;
    for (int e = i; e < N_EDGES; e += stride) {
        int r = rows[e];
        if (r >= lo && r < hi) {
            int pos = atomicAdd(&cursor[r], 1);
            rec[pos] = make_int2(cols[e], __float_as_int(vals[e]));
        }
    }
}

// ---------------- gather SpMM: 16 lanes per row, float4 each, unroll 8 -------
__global__ __launch_bounds__(256) void gather_kernel(
    const float* __restrict__ H, const int2* __restrict__ rec,
    const int* __restrict__ row_ptr, float* __restrict__ out)
{
    int row = blockIdx.x * 16 + (threadIdx.x >> 4);
    int fc  = threadIdx.x & 15;
    if (row >= N_NODES) return;

    int start = row_ptr[row];
    int n     = row_ptr[row + 1] - start;
    const int2* R = rec + start;
    const float4* H4 = reinterpret_cast<const float4*>(H);

    float4 acc = make_float4(0.f, 0.f, 0.f, 0.f);
    int e = 0;
    for (; e + 8 <= n; e += 8) {
        int2 r0 = R[e + 0]; int2 r1 = R[e + 1];
        int2 r2 = R[e + 2]; int2 r3 = R[e + 3];
        int2 r4 = R[e + 4]; int2 r5 = R[e + 5];
        int2 r6 = R[e + 6]; int2 r7 = R[e + 7];
        float4 h0 = H4[(long long)r0.x * 16 + fc];
        float4 h1 = H4[(long long)r1.x * 16 + fc];
        float4 h2 = H4[(long long)r2.x * 16 + fc];
        float4 h3 = H4[(long long)r3.x * 16 + fc];
        float4 h4 = H4[(long long)r4.x * 16 + fc];
        float4 h5 = H4[(long long)r5.x * 16 + fc];
        float4 h6 = H4[(long long)r6.x * 16 + fc];
        float4 h7 = H4[(long long)r7.x * 16 + fc];
        float v0 = __int_as_float(r0.y); float v1 = __int_as_float(r1.y);
        float v2 = __int_as_float(r2.y); float v3 = __int_as_float(r3.y);
        float v4 = __int_as_float(r4.y); float v5 = __int_as_float(r5.y);
        float v6 = __int_as_float(r6.y); float v7 = __int_as_float(r7.y);
        acc.x += v0 * h0.x; acc.y += v0 * h0.y; acc.z += v0 * h0.z; acc.w += v0 * h0.w;
        acc.x += v1 * h1.x; acc.y += v1 * h1.y; acc.z += v1 * h1.z; acc.w += v1 * h1.w;
        acc.x += v2 * h2.x; acc.y += v2 * h2.y; acc.z += v2 * h2.z; acc.w += v2 * h2.w;
        acc.x += v3 * h3.x; acc.y += v3 * h3.y; acc.z += v3 * h3.z; acc.w += v3 * h3.w;
        acc.x += v4 * h4.x; acc.y += v4 * h4.y; acc.z += v4 * h4.z; acc.w += v4 * h4.w;
        acc.x += v5 * h5.x; acc.y += v5 * h5.y; acc.z += v5 * h5.z; acc.w += v5 * h5.w;
        acc.x += v6 * h6.x; acc.y += v6 * h6.y; acc.z += v6 * h6.z; acc.w += v6 * h6.w;
        acc.x += v7 * h7.x; acc.y += v7 * h7.y; acc.z += v7 * h7.z; acc.w += v7 * h7.w;
    }
    for (; e < n; ++e) {
        int2 r0 = R[e];
        float4 h0 = H4[(long long)r0.x * 16 + fc];
        float v0 = __int_as_float(r0.y);
        acc.x += v0 * h0.x; acc.y += v0 * h0.y; acc.z += v0 * h0.z; acc.w += v0 * h0.w;
    }
    reinterpret_cast<float4*>(out)[(long long)row * 16 + fc] = acc;
}

extern "C" void kernel_launch(void* const* d_in, const int* in_sizes, int n_in,
                              void* d_out, int out_size, void* d_ws, size_t ws_size,
                              hipStream_t stream) {
    const float* H    = (const float*)d_in[0];
    const float* vals = (const float*)d_in[1];
    const int*   rows = (const int*)d_in[2];
    const int*   cols = (const int*)d_in[3];
    float* out = (float*)d_out;

    // workspace layout: rec first (8B aligned), then int arrays
    char* ws = (char*)d_ws;
    int2* rec       = (int2*)ws;                          // E * 8B
    int*  row_ptr   = (int*)(rec + N_EDGES);              // N+1
    int*  cursor    = row_ptr + (N_NODES + 1);            // N
    int*  blocksums = cursor + N_NODES;                   // SCAN_GRID

    int* counts = cursor;  // histogram counts live in cursor region

    hipMemsetAsync(counts, 0, N_NODES * sizeof(int), stream);

    hist_kernel<<<512, 256, 0, stream>>>(rows, counts);
    scanA_kernel<<<SCAN_GRID, SCAN_BLOCK, 0, stream>>>(counts, row_ptr, blocksums);
    scanB_kernel<<<1, 128, 0, stream>>>(blocksums);
    scanC_kernel<<<SCAN_GRID, SCAN_BLOCK, 0, stream>>>(row_ptr, blocksums, cursor);
    scatter_kernel<<<512, 256, 0, stream>>>(vals, rows, cols, cursor, rec);

    int gather_grid = (N_NODES + 15) / 16;  // 16 rows per 256-thread block
    gather_kernel<<<gather_grid, 256, 0, stream>>>(H, rec, row_ptr, out);
}